// Round 3
// baseline (3777.149 us; speedup 1.0000x reference)
//
#include <hip/hip_runtime.h>
#include <hip/hip_bf16.h>

typedef __hip_bfloat16 bf16;
typedef float v4f __attribute__((ext_vector_type(4)));
typedef __attribute__((ext_vector_type(8))) short short8;

__device__ __forceinline__ float b2f(bf16 v) { return __bfloat162float(v); }
__device__ __forceinline__ bf16 f2b(float v) { return __float2bfloat16(v); }

// Problem constants
#define BB 32
#define CD 384
#define HH 56
#define ND 3136        // 56*56
#define HID 1536
#define GG 7
#define SS 8
#define MROWS 100352   // BB*ND

// window-row (w*64+t) -> token-row (b*ND + n)
__device__ __forceinline__ int wrow_to_token(int orow) {
    int w = orow >> 6, t = orow & 63;
    int bb = w / 49, wr = w % 49;
    int gy = wr / GG, gx = wr % GG;
    int sy = t >> 3, sx = t & 7;
    return bb * ND + (sy * GG + gy) * HH + (sx * GG + gx);
}

// ---------- batched transpose fp32 -> bf16: in[b][r][c] (f32) -> out[b][c][r] (bf16) ----------
__global__ __launch_bounds__(256) void transpose_f2b_k(const float* __restrict__ in,
                                                       bf16* __restrict__ out, int R, int Cc)
{
    __shared__ float tile[32][33];
    int c0 = blockIdx.x * 32, r0 = blockIdx.y * 32;
    size_t bb = blockIdx.z;
    int tx = threadIdx.x & 31, ty = threadIdx.x >> 5;
    const float* ip = in + bb * (size_t)R * Cc;
    bf16* op = out + bb * (size_t)R * Cc;
#pragma unroll
    for (int i = 0; i < 4; i++)
        tile[ty + i * 8][tx] = ip[(size_t)(r0 + ty + i * 8) * Cc + (c0 + tx)];
    __syncthreads();
#pragma unroll
    for (int i = 0; i < 4; i++)
        op[(size_t)(c0 + ty + i * 8) * R + (r0 + tx)] = f2b(tile[tx][ty + i * 8]);
}

// ---------- LayerNorm over C=384, one wave per output row; chunked ----------
__global__ __launch_bounds__(256) void ln_k(const bf16* __restrict__ in,
                                            const float* __restrict__ g,
                                            const float* __restrict__ b,
                                            bf16* __restrict__ out,
                                            int row0, int gather)
{
    int wave = threadIdx.x >> 6, lane = threadIdx.x & 63;
    int row = row0 + blockIdx.x * 4 + wave;
    int src = gather ? wrow_to_token(row) : row;
    const bf16* ip = in + (size_t)src * CD;
    float vals[6];
    float s = 0.f, s2 = 0.f;
#pragma unroll
    for (int i = 0; i < 6; i++) {
        float v = b2f(ip[lane + i * 64]);
        vals[i] = v; s += v; s2 += v * v;
    }
#pragma unroll
    for (int off = 32; off >= 1; off >>= 1) {
        s  += __shfl_xor(s, off);
        s2 += __shfl_xor(s2, off);
    }
    float mean = s * (1.f / CD);
    float var = s2 * (1.f / CD) - mean * mean;
    float rstd = rsqrtf(var + 1e-5f);
    bf16* op = out + (size_t)(row - row0) * CD;
#pragma unroll
    for (int i = 0; i < 6; i++) {
        int c = lane + i * 64;
        op[c] = f2b((vals[i] - mean) * rstd * g[c] + b[c]);
    }
}

// ---------- GEMM: C[M,N] = A[M,K] @ Bt[N,K]^T (+fp32 bias per col), bf16 in, fp32 acc ----------
__global__ __launch_bounds__(256) void gemm_bt(const bf16* __restrict__ A,
                                               const bf16* __restrict__ Bt,
                                               const float* __restrict__ bias,
                                               bf16* __restrict__ Cm,
                                               int M, int N, int K)
{
    __shared__ __align__(16) bf16 As[128][40];
    __shared__ __align__(16) bf16 Bs[128][40];
    const int tid = threadIdx.x;
    const int m0 = blockIdx.y * 128, n0 = blockIdx.x * 128;
    const int lane = tid & 63, wave = tid >> 6;
    const int rb = (wave >> 1) * 64, cb = (wave & 1) * 64;
    const int lr = lane & 15, ko = (lane >> 4) * 8;

    v4f acc[4][4];
#pragma unroll
    for (int i = 0; i < 4; i++)
#pragma unroll
        for (int j = 0; j < 4; j++) acc[i][j] = (v4f)0.f;

    for (int kk = 0; kk < K; kk += 32) {
        for (int ch = tid; ch < 512; ch += 256) {
            int row = ch >> 2, off = (ch & 3) * 8;
            *(uint4*)&As[row][off] = *(const uint4*)&A [(size_t)(m0 + row) * K + kk + off];
            *(uint4*)&Bs[row][off] = *(const uint4*)&Bt[(size_t)(n0 + row) * K + kk + off];
        }
        __syncthreads();
        short8 af[4], bfr[4];
#pragma unroll
        for (int mi = 0; mi < 4; mi++) af[mi]  = *(const short8*)&As[rb + mi * 16 + lr][ko];
#pragma unroll
        for (int ni = 0; ni < 4; ni++) bfr[ni] = *(const short8*)&Bs[cb + ni * 16 + lr][ko];
#pragma unroll
        for (int mi = 0; mi < 4; mi++)
#pragma unroll
            for (int ni = 0; ni < 4; ni++)
                acc[mi][ni] = __builtin_amdgcn_mfma_f32_16x16x32_bf16(af[mi], bfr[ni], acc[mi][ni], 0, 0, 0);
        __syncthreads();
    }
#pragma unroll
    for (int ni = 0; ni < 4; ni++) {
        int col = n0 + cb + ni * 16 + lr;
        float bv = bias ? bias[col] : 0.f;
#pragma unroll
        for (int mi = 0; mi < 4; mi++) {
            int rowb = m0 + rb + mi * 16 + (lane >> 4) * 4;
#pragma unroll
            for (int r = 0; r < 4; r++)
                Cm[(size_t)(rowb + r) * N + col] = f2b(acc[mi][ni][r] + bv);
        }
    }
}

// ---------- attention on a chunk: one block per (local window, head); n=64, hd=48 ----------
__global__ __launch_bounds__(256) void attn_k(const bf16* __restrict__ qkv, bf16* __restrict__ o)
{
    __shared__ float qs[64][49], ks[64][49], vs[64][49];
    __shared__ float sc[64][65];
    int lw = blockIdx.x >> 3, head = blockIdx.x & 7;
    const bf16* base = qkv + (size_t)lw * 64 * 1152 + head * 48;
    for (int idx = threadIdx.x; idx < 64 * 48; idx += 256) {
        int t = idx / 48, d = idx % 48;
        const bf16* p = base + (size_t)t * 1152 + d;
        qs[t][d] = b2f(p[0]);
        ks[t][d] = b2f(p[384]);
        vs[t][d] = b2f(p[768]);
    }
    __syncthreads();
    const float scale = 0.14433756729740643f; // 48^-0.5
    for (int e = threadIdx.x; e < 4096; e += 256) {
        int i = e >> 6, j = e & 63;
        float dot = 0.f;
#pragma unroll
        for (int d = 0; d < 48; d++) dot += qs[i][d] * ks[j][d];
        sc[i][j] = dot * scale;
    }
    __syncthreads();
    if (threadIdx.x < 64) {
        int i = threadIdx.x;
        float mx = -1e30f;
#pragma unroll
        for (int j = 0; j < 64; j++) mx = fmaxf(mx, sc[i][j]);
        float sum = 0.f;
#pragma unroll
        for (int j = 0; j < 64; j++) { float e = __expf(sc[i][j] - mx); sc[i][j] = e; sum += e; }
        float inv = 1.f / sum;
#pragma unroll
        for (int j = 0; j < 64; j++) sc[i][j] *= inv;
    }
    __syncthreads();
    for (int e = threadIdx.x; e < 64 * 48; e += 256) {
        int i = e / 48, d = e % 48;
        float accv = 0.f;
#pragma unroll
        for (int j = 0; j < 64; j++) accv += sc[i][j] * vs[j][d];
        o[((size_t)lw * 64 + i) * CD + head * 48 + d] = f2b(accv);
    }
}

// ---------- residual 1 (chunk): x1[token,c] = xt[token,c] + gamma1[c]*oprojc[lrow,c] ----------
__global__ __launch_bounds__(256) void resid1_k(const bf16* __restrict__ xt,
                                                const bf16* __restrict__ oprojc,
                                                const float* __restrict__ gamma1,
                                                bf16* __restrict__ x1, int row0)
{
    int idx = blockIdx.x * 256 + threadIdx.x; // < Mc*CD
    int lrow = idx / CD, c = idx % CD;
    int token = wrow_to_token(row0 + lrow);
    size_t xi = (size_t)token * CD + c;
    x1[xi] = f2b(b2f(xt[xi]) + gamma1[c] * b2f(oprojc[idx]));
}

// ---------- depthwise 3x3 conv + bias + exact GELU on a chunk (whole images) ----------
__global__ __launch_bounds__(256) void dwconv_gelu_k(const bf16* __restrict__ m1c,
                                                     const float* __restrict__ wgt,
                                                     const float* __restrict__ bias,
                                                     bf16* __restrict__ gc)
{
    size_t idx = (size_t)blockIdx.x * 256 + threadIdx.x; // < nb*ND*HID
    int ch = (int)(idx % HID);
    int tok = (int)(idx / HID);     // local token
    int lb = tok / ND, n = tok % ND;
    int hh = n / HH, ww = n % HH;
    float accv = bias[ch];
#pragma unroll
    for (int dy = 0; dy < 3; dy++) {
        int y = hh + dy - 1;
        if (y < 0 || y >= HH) continue;
#pragma unroll
        for (int dx = 0; dx < 3; dx++) {
            int x = ww + dx - 1;
            if (x < 0 || x >= HH) continue;
            accv += wgt[ch * 9 + dy * 3 + dx] *
                    b2f(m1c[((size_t)lb * ND + y * HH + x) * HID + ch]);
        }
    }
    float ge = 0.5f * accv * (1.f + erff(accv * 0.70710678118654752f));
    gc[idx] = f2b(ge);
}

// ---------- residual 2 + transpose to NCHW fp32 output (chunk of nb images at b0) ----------
__global__ __launch_bounds__(256) void resid2_k(const bf16* __restrict__ x1,
                                                const bf16* __restrict__ m2c,
                                                const float* __restrict__ gamma2,
                                                float* __restrict__ out, int b0)
{
    __shared__ float tile[32][33];
    int n0 = blockIdx.x * 32, c0 = blockIdx.y * 32;
    int lb = blockIdx.z, gb = b0 + lb;
    int tx = threadIdx.x & 31, ty = threadIdx.x >> 5;
#pragma unroll
    for (int i = 0; i < 4; i++) {
        int n = n0 + ty + i * 8, c = c0 + tx;
        size_t sx1 = ((size_t)gb * ND + n) * CD + c;
        size_t sm  = ((size_t)lb * ND + n) * CD + c;
        tile[ty + i * 8][tx] = b2f(x1[sx1]) + gamma2[c] * b2f(m2c[sm]);
    }
    __syncthreads();
#pragma unroll
    for (int i = 0; i < 4; i++) {
        int c = c0 + ty + i * 8, n = n0 + tx;
        out[((size_t)gb * CD + c) * ND + n] = tile[tx][ty + i * 8];
    }
}

extern "C" void kernel_launch(void* const* d_in, const int* in_sizes, int n_in,
                              void* d_out, int out_size, void* d_ws, size_t ws_size,
                              hipStream_t stream) {
    const float* x      = (const float*)d_in[0];
    const float* ln1_g  = (const float*)d_in[1];
    const float* ln1_b  = (const float*)d_in[2];
    const float* qkv_w  = (const float*)d_in[3];
    const float* proj_w = (const float*)d_in[4];
    const float* proj_b = (const float*)d_in[5];
    const float* ln2_g  = (const float*)d_in[6];
    const float* ln2_b  = (const float*)d_in[7];
    const float* fc1_w  = (const float*)d_in[8];
    const float* fc1_b  = (const float*)d_in[9];
    const float* dw_w   = (const float*)d_in[10];
    const float* dw_b   = (const float*)d_in[11];
    const float* fc2_w  = (const float*)d_in[12];
    const float* fc2_b  = (const float*)d_in[13];
    const float* gamma1 = (const float*)d_in[14];
    const float* gamma2 = (const float*)d_in[15];
    float* out = (float*)d_out;

    // ---- workspace layout (same 201 MB footprint that ran in round 2) ----
    const size_t SZ_TOK = (size_t)MROWS * CD * 2;   // 77,070,336 (bf16 token-major)
    const size_t S0 = 2 * SZ_TOK;
    const int CA = 8, McA = MROWS / CA;             // 12544 = 98*128
    const size_t sz_h  = (size_t)McA * CD * 2;      // 9,633,792
    const size_t sz_qk = (size_t)McA * 1152 * 2;    // 28,901,376
    const size_t attn_end = S0 + sz_h + sz_qk;
    int cm = 16;
    {
        size_t mc2 = (size_t)(BB / 8) * ND;
        size_t mlp_end8 = S0 + mc2 * CD * 2 + 2 * mc2 * HID * 2;
        size_t tot8 = (mlp_end8 > attn_end ? mlp_end8 : attn_end) + 3538944;
        if (ws_size >= tot8) cm = 8;
    }
    const int nb = BB / cm;
    const int Mc2 = nb * ND;
    const size_t sz_h2 = (size_t)Mc2 * CD * 2;
    const size_t sz_m1 = (size_t)Mc2 * HID * 2;
    const size_t mlp_end = S0 + sz_h2 + 2 * sz_m1;
    const size_t Wo = (mlp_end > attn_end ? mlp_end : attn_end);
    const size_t total = Wo + 3538944;
    if (ws_size < total) return;

    char* w = (char*)d_ws;
    bf16* xt      = (bf16*)(w + 0);
    bf16* x1      = (bf16*)(w + SZ_TOK);
    bf16* hc      = (bf16*)(w + S0);                // attention: h / o (aliased)
    bf16* qkvc    = (bf16*)(w + S0 + sz_h);         // attention: qkv / oproj (aliased)
    bf16* h2c     = (bf16*)(w + S0);                // MLP: h2 / m2 (aliased)
    bf16* m1c     = (bf16*)(w + S0 + sz_h2);
    bf16* gc      = (bf16*)(w + S0 + sz_h2 + sz_m1);
    bf16* qkv_wt  = (bf16*)(w + Wo);
    bf16* proj_wt = (bf16*)(w + Wo + 884736);
    bf16* fc1_wt  = (bf16*)(w + Wo + 884736 + 294912);
    bf16* fc2_wt  = (bf16*)(w + Wo + 884736 + 294912 + 1179648);

    dim3 blk(256);

    // fp32 -> bf16 transposes: x -> xt (token-major), weights -> K-contiguous (B^T)
    transpose_f2b_k<<<dim3(98, 12, 32), blk, 0, stream>>>(x, xt, CD, ND);
    transpose_f2b_k<<<dim3(36, 12, 1), blk, 0, stream>>>(qkv_w, qkv_wt, CD, 1152);
    transpose_f2b_k<<<dim3(12, 12, 1), blk, 0, stream>>>(proj_w, proj_wt, CD, CD);
    transpose_f2b_k<<<dim3(48, 12, 1), blk, 0, stream>>>(fc1_w, fc1_wt, CD, HID);
    transpose_f2b_k<<<dim3(12, 48, 1), blk, 0, stream>>>(fc2_w, fc2_wt, HID, CD);

    // ---- attention phase: 8 chunks of McA window rows ----
    for (int ch = 0; ch < CA; ch++) {
        int row0 = ch * McA;
        ln_k<<<McA / 4, blk, 0, stream>>>(xt, ln1_g, ln1_b, hc, row0, 1);
        gemm_bt<<<dim3(9, McA / 128), blk, 0, stream>>>(hc, qkv_wt, nullptr, qkvc, McA, 1152, CD);
        attn_k<<<(McA / 64) * 8, blk, 0, stream>>>(qkvc, hc);           // o -> hc
        gemm_bt<<<dim3(3, McA / 128), blk, 0, stream>>>(hc, proj_wt, proj_b, qkvc, McA, CD, CD);
        resid1_k<<<(McA * CD) / 256, blk, 0, stream>>>(xt, qkvc, gamma1, x1, row0);
    }

    // ---- MLP phase: cm chunks of nb whole images ----
    for (int ch = 0; ch < cm; ch++) {
        int r0 = ch * Mc2, b0 = ch * nb;
        ln_k<<<Mc2 / 4, blk, 0, stream>>>(x1, ln2_g, ln2_b, h2c, r0, 0);
        gemm_bt<<<dim3(12, Mc2 / 128), blk, 0, stream>>>(h2c, fc1_wt, fc1_b, m1c, Mc2, HID, CD);
        dwconv_gelu_k<<<(Mc2 * (HID / 256)), blk, 0, stream>>>(m1c, dw_w, dw_b, gc);
        gemm_bt<<<dim3(3, Mc2 / 128), blk, 0, stream>>>(gc, fc2_wt, fc2_b, h2c, Mc2, CD, HID);
        resid2_k<<<dim3(98, 12, nb), blk, 0, stream>>>(x1, h2c, gamma2, out, b0);
    }
}

// Round 4
// 2879.705 us; speedup vs baseline: 1.3116x; 1.3116x over previous
//
#include <hip/hip_runtime.h>
#include <hip/hip_bf16.h>

typedef __hip_bfloat16 bf16;
typedef float v4f __attribute__((ext_vector_type(4)));
typedef __attribute__((ext_vector_type(8))) short short8;

__device__ __forceinline__ float b2f(bf16 v) { return __bfloat162float(v); }
__device__ __forceinline__ bf16 f2b(float v) { return __float2bfloat16(v); }

// Problem constants
#define BB 32
#define CD 384
#define HH 56
#define ND 3136        // 56*56
#define HID 1536
#define GG 7
#define SS 8
#define MROWS 100352   // BB*ND

// window-row (w*64+t) -> token-row (b*ND + n)
__device__ __forceinline__ int wrow_to_token(int orow) {
    int w = orow >> 6, t = orow & 63;
    int bb = w / 49, wr = w % 49;
    int gy = wr / GG, gx = wr % GG;
    int sy = t >> 3, sx = t & 7;
    return bb * ND + (sy * GG + gy) * HH + (sx * GG + gx);
}

// ---------- batched transpose fp32 -> bf16: in[b][r][c] (f32) -> out[b][c][r] (bf16) ----------
__global__ __launch_bounds__(256) void transpose_f2b_k(const float* __restrict__ in,
                                                       bf16* __restrict__ out, int R, int Cc)
{
    __shared__ float tile[32][33];
    int c0 = blockIdx.x * 32, r0 = blockIdx.y * 32;
    size_t bb = blockIdx.z;
    int tx = threadIdx.x & 31, ty = threadIdx.x >> 5;
    const float* ip = in + bb * (size_t)R * Cc;
    bf16* op = out + bb * (size_t)R * Cc;
#pragma unroll
    for (int i = 0; i < 4; i++)
        tile[ty + i * 8][tx] = ip[(size_t)(r0 + ty + i * 8) * Cc + (c0 + tx)];
    __syncthreads();
#pragma unroll
    for (int i = 0; i < 4; i++)
        op[(size_t)(c0 + ty + i * 8) * R + (r0 + tx)] = f2b(tile[tx][ty + i * 8]);
}

// ---------- LayerNorm over C=384, one wave per output row; chunked ----------
__global__ __launch_bounds__(256) void ln_k(const bf16* __restrict__ in,
                                            const float* __restrict__ g,
                                            const float* __restrict__ b,
                                            bf16* __restrict__ out,
                                            int row0, int gather)
{
    int wave = threadIdx.x >> 6, lane = threadIdx.x & 63;
    int row = row0 + blockIdx.x * 4 + wave;
    int src = gather ? wrow_to_token(row) : row;
    const bf16* ip = in + (size_t)src * CD;
    float vals[6];
    float s = 0.f, s2 = 0.f;
#pragma unroll
    for (int i = 0; i < 6; i++) {
        float v = b2f(ip[lane + i * 64]);
        vals[i] = v; s += v; s2 += v * v;
    }
#pragma unroll
    for (int off = 32; off >= 1; off >>= 1) {
        s  += __shfl_xor(s, off);
        s2 += __shfl_xor(s2, off);
    }
    float mean = s * (1.f / CD);
    float var = s2 * (1.f / CD) - mean * mean;
    float rstd = rsqrtf(var + 1e-5f);
    bf16* op = out + (size_t)(row - row0) * CD;
#pragma unroll
    for (int i = 0; i < 6; i++) {
        int c = lane + i * 64;
        op[c] = f2b((vals[i] - mean) * rstd * g[c] + b[c]);
    }
}

// ---------- GEMM: C[M,N] = A[M,K] @ Bt[N,K]^T (+fp32 bias per col), bf16 in, fp32 acc ----------
__global__ __launch_bounds__(256) void gemm_bt(const bf16* __restrict__ A,
                                               const bf16* __restrict__ Bt,
                                               const float* __restrict__ bias,
                                               bf16* __restrict__ Cm,
                                               int M, int N, int K)
{
    __shared__ __align__(16) bf16 As[128][40];
    __shared__ __align__(16) bf16 Bs[128][40];
    const int tid = threadIdx.x;
    const int m0 = blockIdx.y * 128, n0 = blockIdx.x * 128;
    const int lane = tid & 63, wave = tid >> 6;
    const int rb = (wave >> 1) * 64, cb = (wave & 1) * 64;
    const int lr = lane & 15, ko = (lane >> 4) * 8;

    v4f acc[4][4];
#pragma unroll
    for (int i = 0; i < 4; i++)
#pragma unroll
        for (int j = 0; j < 4; j++) acc[i][j] = (v4f)0.f;

    for (int kk = 0; kk < K; kk += 32) {
        for (int ch = tid; ch < 512; ch += 256) {
            int row = ch >> 2, off = (ch & 3) * 8;
            *(uint4*)&As[row][off] = *(const uint4*)&A [(size_t)(m0 + row) * K + kk + off];
            *(uint4*)&Bs[row][off] = *(const uint4*)&Bt[(size_t)(n0 + row) * K + kk + off];
        }
        __syncthreads();
        short8 af[4], bfr[4];
#pragma unroll
        for (int mi = 0; mi < 4; mi++) af[mi]  = *(const short8*)&As[rb + mi * 16 + lr][ko];
#pragma unroll
        for (int ni = 0; ni < 4; ni++) bfr[ni] = *(const short8*)&Bs[cb + ni * 16 + lr][ko];
#pragma unroll
        for (int mi = 0; mi < 4; mi++)
#pragma unroll
            for (int ni = 0; ni < 4; ni++)
                acc[mi][ni] = __builtin_amdgcn_mfma_f32_16x16x32_bf16(af[mi], bfr[ni], acc[mi][ni], 0, 0, 0);
        __syncthreads();
    }
#pragma unroll
    for (int ni = 0; ni < 4; ni++) {
        int col = n0 + cb + ni * 16 + lr;
        float bv = bias ? bias[col] : 0.f;
#pragma unroll
        for (int mi = 0; mi < 4; mi++) {
            int rowb = m0 + rb + mi * 16 + (lane >> 4) * 4;
#pragma unroll
            for (int r = 0; r < 4; r++)
                Cm[(size_t)(rowb + r) * N + col] = f2b(acc[mi][ni][r] + bv);
        }
    }
}

// ---------- attention on a chunk: one block per (local window, head); n=64, hd=48 ----------
__global__ __launch_bounds__(256) void attn_k(const bf16* __restrict__ qkv, bf16* __restrict__ o)
{
    __shared__ float qs[64][49], ks[64][49], vs[64][49];
    __shared__ float sc[64][65];
    int lw = blockIdx.x >> 3, head = blockIdx.x & 7;
    const bf16* base = qkv + (size_t)lw * 64 * 1152 + head * 48;
    for (int idx = threadIdx.x; idx < 64 * 48; idx += 256) {
        int t = idx / 48, d = idx % 48;
        const bf16* p = base + (size_t)t * 1152 + d;
        qs[t][d] = b2f(p[0]);
        ks[t][d] = b2f(p[384]);
        vs[t][d] = b2f(p[768]);
    }
    __syncthreads();
    const float scale = 0.14433756729740643f; // 48^-0.5
    for (int e = threadIdx.x; e < 4096; e += 256) {
        int i = e >> 6, j = e & 63;
        float dot = 0.f;
#pragma unroll
        for (int d = 0; d < 48; d++) dot += qs[i][d] * ks[j][d];
        sc[i][j] = dot * scale;
    }
    __syncthreads();
    if (threadIdx.x < 64) {
        int i = threadIdx.x;
        float mx = -1e30f;
#pragma unroll
        for (int j = 0; j < 64; j++) mx = fmaxf(mx, sc[i][j]);
        float sum = 0.f;
#pragma unroll
        for (int j = 0; j < 64; j++) { float e = __expf(sc[i][j] - mx); sc[i][j] = e; sum += e; }
        float inv = 1.f / sum;
#pragma unroll
        for (int j = 0; j < 64; j++) sc[i][j] *= inv;
    }
    __syncthreads();
    for (int e = threadIdx.x; e < 64 * 48; e += 256) {
        int i = e / 48, d = e % 48;
        float accv = 0.f;
#pragma unroll
        for (int j = 0; j < 64; j++) accv += sc[i][j] * vs[j][d];
        o[((size_t)lw * 64 + i) * CD + head * 48 + d] = f2b(accv);
    }
}

// ---------- residual 1 (chunk): x1[token,c] = xt[token,c] + gamma1[c]*oprojc[lrow,c] ----------
__global__ __launch_bounds__(256) void resid1_k(const bf16* __restrict__ xt,
                                                const bf16* __restrict__ oprojc,
                                                const float* __restrict__ gamma1,
                                                bf16* __restrict__ x1, int row0)
{
    int idx = blockIdx.x * 256 + threadIdx.x; // < Mc*CD
    int lrow = idx / CD, c = idx % CD;
    int token = wrow_to_token(row0 + lrow);
    size_t xi = (size_t)token * CD + c;
    x1[xi] = f2b(b2f(xt[xi]) + gamma1[c] * b2f(oprojc[idx]));
}

// ---------- depthwise 3x3 conv + bias + exact GELU: register sliding window ----------
// grid: x = HID/64 ch-groups, y = 7 x-groups (8 px each), z = nb*4 (image, y-strip of 14)
// thread: one channel, two adjacent x positions; slides y down the strip.
__global__ __launch_bounds__(256) void dwconv_gelu_k(const bf16* __restrict__ m1c,
                                                     const float* __restrict__ wgt,
                                                     const float* __restrict__ bias,
                                                     bf16* __restrict__ gc)
{
    const int c  = blockIdx.x * 64 + (threadIdx.x & 63);
    const int xq = threadIdx.x >> 6;
    const int xx = blockIdx.y * 8 + xq * 2;     // first of 2 x positions (<= 54)
    const int lb = blockIdx.z >> 2;
    const int ys = (blockIdx.z & 3) * 14;

    float w9[9];
#pragma unroll
    for (int i = 0; i < 9; i++) w9[i] = wgt[c * 9 + i];
    const float bs = bias[c];

    const bf16* base = m1c + (size_t)lb * ND * HID + c;
    bool  v[4];
    const bf16* colp[4];
#pragma unroll
    for (int i = 0; i < 4; i++) {
        int xc = xx - 1 + i;
        v[i] = (xc >= 0 && xc < HH);
        int xcl = xc < 0 ? 0 : (xc > HH - 1 ? HH - 1 : xc);
        colp[i] = base + (size_t)xcl * HID;
    }
    const size_t ystride = (size_t)HH * HID;

    float win[3][4];
    // preload rows ys-1 and ys
    {
        int ym = ys - 1;
        int ymc = ym < 0 ? 0 : ym;
        bool yv = (ym >= 0);
#pragma unroll
        for (int i = 0; i < 4; i++)
            win[0][i] = (yv && v[i]) ? b2f(colp[i][(size_t)ymc * ystride]) : 0.f;
#pragma unroll
        for (int i = 0; i < 4; i++)
            win[1][i] = v[i] ? b2f(colp[i][(size_t)ys * ystride]) : 0.f;
    }

#pragma unroll
    for (int s = 0; s < 14; s++) {
        const int y = ys + s;
        const int yp = y + 1;
        const bool yv = (yp < HH);
        const int ypc = yv ? yp : (HH - 1);
#pragma unroll
        for (int i = 0; i < 4; i++)
            win[2][i] = (yv && v[i]) ? b2f(colp[i][(size_t)ypc * ystride]) : 0.f;

        float a0 = bs, a1 = bs;
#pragma unroll
        for (int r = 0; r < 3; r++)
#pragma unroll
            for (int j = 0; j < 3; j++) {
                a0 = fmaf(w9[r * 3 + j], win[r][j],     a0);
                a1 = fmaf(w9[r * 3 + j], win[r][j + 1], a1);
            }
        float g0 = 0.5f * a0 * (1.f + erff(a0 * 0.70710678118654752f));
        float g1 = 0.5f * a1 * (1.f + erff(a1 * 0.70710678118654752f));
        size_t o0 = ((size_t)lb * ND + (size_t)y * HH + xx) * HID + c;
        gc[o0]       = f2b(g0);
        gc[o0 + HID] = f2b(g1);

#pragma unroll
        for (int i = 0; i < 4; i++) { win[0][i] = win[1][i]; win[1][i] = win[2][i]; }
    }
}

// ---------- residual 2 + transpose to NCHW fp32 output (chunk of nb images at b0) ----------
__global__ __launch_bounds__(256) void resid2_k(const bf16* __restrict__ x1,
                                                const bf16* __restrict__ m2c,
                                                const float* __restrict__ gamma2,
                                                float* __restrict__ out, int b0)
{
    __shared__ float tile[32][33];
    int n0 = blockIdx.x * 32, c0 = blockIdx.y * 32;
    int lb = blockIdx.z, gb = b0 + lb;
    int tx = threadIdx.x & 31, ty = threadIdx.x >> 5;
#pragma unroll
    for (int i = 0; i < 4; i++) {
        int n = n0 + ty + i * 8, c = c0 + tx;
        size_t sx1 = ((size_t)gb * ND + n) * CD + c;
        size_t sm  = ((size_t)lb * ND + n) * CD + c;
        tile[ty + i * 8][tx] = b2f(x1[sx1]) + gamma2[c] * b2f(m2c[sm]);
    }
    __syncthreads();
#pragma unroll
    for (int i = 0; i < 4; i++) {
        int c = c0 + ty + i * 8, n = n0 + tx;
        out[((size_t)gb * CD + c) * ND + n] = tile[tx][ty + i * 8];
    }
}

extern "C" void kernel_launch(void* const* d_in, const int* in_sizes, int n_in,
                              void* d_out, int out_size, void* d_ws, size_t ws_size,
                              hipStream_t stream) {
    const float* x      = (const float*)d_in[0];
    const float* ln1_g  = (const float*)d_in[1];
    const float* ln1_b  = (const float*)d_in[2];
    const float* qkv_w  = (const float*)d_in[3];
    const float* proj_w = (const float*)d_in[4];
    const float* proj_b = (const float*)d_in[5];
    const float* ln2_g  = (const float*)d_in[6];
    const float* ln2_b  = (const float*)d_in[7];
    const float* fc1_w  = (const float*)d_in[8];
    const float* fc1_b  = (const float*)d_in[9];
    const float* dw_w   = (const float*)d_in[10];
    const float* dw_b   = (const float*)d_in[11];
    const float* fc2_w  = (const float*)d_in[12];
    const float* fc2_b  = (const float*)d_in[13];
    const float* gamma1 = (const float*)d_in[14];
    const float* gamma2 = (const float*)d_in[15];
    float* out = (float*)d_out;

    // ---- workspace layout (same footprint that ran in round 3) ----
    const size_t SZ_TOK = (size_t)MROWS * CD * 2;   // 77,070,336 (bf16 token-major)
    const size_t S0 = 2 * SZ_TOK;
    const int CA = 8, McA = MROWS / CA;             // 12544 = 98*128
    const size_t sz_h  = (size_t)McA * CD * 2;      // 9,633,792
    const size_t sz_qk = (size_t)McA * 1152 * 2;    // 28,901,376
    const size_t attn_end = S0 + sz_h + sz_qk;
    int cm = 16;
    {
        size_t mc2 = (size_t)(BB / 8) * ND;
        size_t mlp_end8 = S0 + mc2 * CD * 2 + 2 * mc2 * HID * 2;
        size_t tot8 = (mlp_end8 > attn_end ? mlp_end8 : attn_end) + 3538944;
        if (ws_size >= tot8) cm = 8;
    }
    const int nb = BB / cm;
    const int Mc2 = nb * ND;
    const size_t sz_h2 = (size_t)Mc2 * CD * 2;
    const size_t sz_m1 = (size_t)Mc2 * HID * 2;
    const size_t mlp_end = S0 + sz_h2 + 2 * sz_m1;
    const size_t Wo = (mlp_end > attn_end ? mlp_end : attn_end);
    const size_t total = Wo + 3538944;
    if (ws_size < total) return;

    char* w = (char*)d_ws;
    bf16* xt      = (bf16*)(w + 0);
    bf16* x1      = (bf16*)(w + SZ_TOK);
    bf16* hc      = (bf16*)(w + S0);                // attention: h / o (aliased)
    bf16* qkvc    = (bf16*)(w + S0 + sz_h);         // attention: qkv / oproj (aliased)
    bf16* h2c     = (bf16*)(w + S0);                // MLP: h2 / m2 (aliased)
    bf16* m1c     = (bf16*)(w + S0 + sz_h2);
    bf16* gc      = (bf16*)(w + S0 + sz_h2 + sz_m1);
    bf16* qkv_wt  = (bf16*)(w + Wo);
    bf16* proj_wt = (bf16*)(w + Wo + 884736);
    bf16* fc1_wt  = (bf16*)(w + Wo + 884736 + 294912);
    bf16* fc2_wt  = (bf16*)(w + Wo + 884736 + 294912 + 1179648);

    dim3 blk(256);

    // fp32 -> bf16 transposes: x -> xt (token-major), weights -> K-contiguous (B^T)
    transpose_f2b_k<<<dim3(98, 12, 32), blk, 0, stream>>>(x, xt, CD, ND);
    transpose_f2b_k<<<dim3(36, 12, 1), blk, 0, stream>>>(qkv_w, qkv_wt, CD, 1152);
    transpose_f2b_k<<<dim3(12, 12, 1), blk, 0, stream>>>(proj_w, proj_wt, CD, CD);
    transpose_f2b_k<<<dim3(48, 12, 1), blk, 0, stream>>>(fc1_w, fc1_wt, CD, HID);
    transpose_f2b_k<<<dim3(12, 48, 1), blk, 0, stream>>>(fc2_w, fc2_wt, HID, CD);

    // ---- attention phase: 8 chunks of McA window rows ----
    for (int ch = 0; ch < CA; ch++) {
        int row0 = ch * McA;
        ln_k<<<McA / 4, blk, 0, stream>>>(xt, ln1_g, ln1_b, hc, row0, 1);
        gemm_bt<<<dim3(9, McA / 128), blk, 0, stream>>>(hc, qkv_wt, nullptr, qkvc, McA, 1152, CD);
        attn_k<<<(McA / 64) * 8, blk, 0, stream>>>(qkvc, hc);           // o -> hc
        gemm_bt<<<dim3(3, McA / 128), blk, 0, stream>>>(hc, proj_wt, proj_b, qkvc, McA, CD, CD);
        resid1_k<<<(McA * CD) / 256, blk, 0, stream>>>(xt, qkvc, gamma1, x1, row0);
    }

    // ---- MLP phase: cm chunks of nb whole images ----
    for (int ch = 0; ch < cm; ch++) {
        int r0 = ch * Mc2, b0 = ch * nb;
        ln_k<<<Mc2 / 4, blk, 0, stream>>>(x1, ln2_g, ln2_b, h2c, r0, 0);
        gemm_bt<<<dim3(12, Mc2 / 128), blk, 0, stream>>>(h2c, fc1_wt, fc1_b, m1c, Mc2, HID, CD);
        dwconv_gelu_k<<<dim3(HID / 64, 7, nb * 4), blk, 0, stream>>>(m1c, dw_w, dw_b, gc);
        gemm_bt<<<dim3(3, Mc2 / 128), blk, 0, stream>>>(gc, fc2_wt, fc2_b, h2c, Mc2, CD, HID);
        resid2_k<<<dim3(98, 12, nb), blk, 0, stream>>>(x1, h2c, gamma2, out, b0);
    }
}